// Round 9
// baseline (3346.651 us; speedup 1.0000x reference)
//
#include <hip/hip_runtime.h>
#include <hip/hip_bf16.h>
#include <math.h>

// Problem constants
#define B_    32
#define IC    512
#define OC    256
#define HW    32
#define OHW   64

// ws layout:
//   xcl  at offset 0:          bf16 [32][34][34][512]  = 37,879,808 B (zero-padded channels-last)
//   Amat at offset 37,879,808: bf16 [1024][4608]       =  9,437,184 B
#define WS_AMAT_OFF 37879808ull

typedef __attribute__((ext_vector_type(8))) short short8;
typedef __attribute__((ext_vector_type(4))) float f32x4;
typedef __attribute__((ext_vector_type(2))) float f32x2;

#define GPTR(x) ((const __attribute__((address_space(1))) char*)(x))
#define LPTR(x) ((__attribute__((address_space(3))) char*)(x))

// ---------------------------------------------------------------------------
// Weight transform. M-row order (oc*4 + p): 4 consecutive C-rows per lane are
// the 4 parities of one oc -> coalesced 2x2 output quads in the epilogue.
__global__ __launch_bounds__(256) void wtrans(const float* __restrict__ w,
                                              __hip_bfloat16* __restrict__ Amat) {
    int t = blockIdx.x * blockDim.x + threadIdx.x;  // 131072 threads
    int ic = t & 511, oc = t >> 9;

    const float gain = 1.0f / sqrtf((float)(IC * 9));
    float wl[3][3];
    const float* wp = w + ((size_t)oc * IC + ic) * 9;
#pragma unroll
    for (int i = 0; i < 3; ++i)
#pragma unroll
        for (int j = 0; j < 3; ++j) wl[i][j] = wp[i * 3 + j] * gain;

    const float f1[4] = {1.f, 3.f, 3.f, 1.f};
    float g2[6][6];
#pragma unroll
    for (int s = 0; s < 6; ++s)
#pragma unroll
        for (int tt = 0; tt < 6; ++tt) {
            float acc = 0.f;
#pragma unroll
            for (int i = 0; i < 3; ++i)
#pragma unroll
                for (int j = 0; j < 3; ++j) {
                    int a = s - 2 + i, b = tt - 2 + j;
                    if (a >= 0 && a < 4 && b >= 0 && b < 4)
                        acc += wl[i][j] * f1[a] * f1[b] * 0.0625f;
                }
            g2[s][tt] = acc;
        }

#pragma unroll
    for (int pm = 0; pm < 2; ++pm)
#pragma unroll
        for (int pn = 0; pn < 2; ++pn)
#pragma unroll
            for (int k = 0; k < 3; ++k)
#pragma unroll
                for (int l = 0; l < 3; ++l) {
                    int p = pm * 2 + pn;
                    size_t idx = ((size_t)(oc * 4 + p) * 4608) + (k * 3 + l) * 512 + ic;
                    Amat[idx] = __float2bfloat16(g2[2 * k + 1 - pm][2 * l + 1 - pn]);
                }
}

// ---------------------------------------------------------------------------
// x (fp32 NCHW) -> xcl (bf16, [b][34][34][512], zero halo), via LDS transpose.
__global__ __launch_bounds__(256) void xprep(const float* __restrict__ x,
                                             __hip_bfloat16* __restrict__ xcl) {
    int blk = blockIdx.x;            // 32*34 blocks
    int b = blk / 34, h = blk % 34;
    __hip_bfloat16* orow = xcl + (size_t)(b * 34 + h) * 34 * 512;
    int t = threadIdx.x;
    bool hin = (h >= 1 && h <= 32);

    for (int i = t; i < 2 * 512; i += 256) {
        int wsel = i >> 9, ic = i & 511;
        orow[(size_t)(wsel * 33) * 512 + ic] = __float2bfloat16(0.f);
    }

    __shared__ float ls[16][33];
    int icl_r = t >> 5, wv_r = t & 31;
    int wv_w = t >> 3, icl_w = t & 7;

    for (int ic0 = 0; ic0 < 512; ic0 += 16) {
        __syncthreads();
#pragma unroll
        for (int pp = 0; pp < 2; ++pp) {
            int icll = icl_r + pp * 8;
            float v = 0.f;
            if (hin) v = x[(((size_t)b * IC + ic0 + icll) * HW + (h - 1)) * HW + wv_r];
            ls[icll][wv_r] = v;
        }
        __syncthreads();
#pragma unroll
        for (int pp = 0; pp < 2; ++pp) {
            int icll = icl_w + pp * 8;
            orow[(size_t)(wv_w + 1) * 512 + ic0 + icll] = __float2bfloat16(ls[icll][wv_w]);
        }
    }
}

// ---------------------------------------------------------------------------
// Implicit-GEMM, 256x256 tile, BK=32, 8 waves (2Mx4N), ring-4 LDS, counted
// vmcnt(4), T2 swizzle (zero-conflict verified R4), T5 setprio, 16x16x32
// engine, register double-buffered fragments (R5), XCD remap (R7), and NEW:
// wave-parity phase stagger — even waves run MFMA(t) then reads(t+1), odd
// waves reads(t+1) then MFMA(t). MFMA blocks its issuing wave (no intra-wave
// overlap), so cross-wave role-split is the only way to keep the MFMA pipe
// and LDS busy simultaneously; lockstep schedules serialize them (R4/R5/R8:
// wall = MFMA + LDS summed).
__global__ __launch_bounds__(512, 2) void gemm_conv(const __hip_bfloat16* __restrict__ Amat,
                                                    const __hip_bfloat16* __restrict__ xcl,
                                                    const float* __restrict__ bias,
                                                    float* __restrict__ out) {
    __shared__ __align__(1024) char lds[4 * 32768];

    const int NT = 144;
    int bid = blockIdx.x;
    // XCD remap (verified R7: FETCH 610->281 MB): all 4 mt sharing a B-panel
    // land on one XCD (bid%8); 16 consecutive blocks sweep nt -> A-panel hot.
    int mt = bid >> 7;               // 0..3
    int nt = (bid & 7) * 16 + ((bid >> 3) & 15);  // 0..127
    int tid = threadIdx.x;
    int wid = tid >> 6;
    int lane = tid & 63;
    int wr = wid >> 2;               // 0..1  (M half)
    int wc = wid & 3;                // 0..3  (N quarter)
    int q = lane >> 4;               // k-granule
    int lr = lane & 15;

    // ---- staging source offsets (swizzle folded into global source) ----
    int rowS = tid >> 2;             // 0..127 (second load: +128)
    int slt = tid & 3;
    int fS = (rowS >> 1) & 3;
    int sgl = slt ^ fS;              // global slot fetched into LDS slot slt

    const char* GA = (const char*)Amat + (size_t)mt * 256 * 9216;
    int offA0 = rowS * 9216 + sgl * 16;
    int offA1 = (rowS + 128) * 9216 + sgl * 16;

    int n0 = nt * 256 + rowS;
    int b0i = n0 >> 10, u0 = (n0 >> 5) & 31, v0 = n0 & 31;
    int n1 = n0 + 128;
    int b1i = n1 >> 10, u1 = (n1 >> 5) & 31, v1 = n1 & 31;
    const char* GB = (const char*)xcl;
    int offB0 = ((b0i * 34 + u0) * 34 + v0) * 1024 + sgl * 16;
    int offB1 = ((b1i * 34 + u1) * 34 + v1) * 1024 + sgl * 16;

    int dA0 = wid * 1024;            // + lane*16 added by HW
    int dA1 = 8192 + wid * 1024;
    int dB0 = 16384 + wid * 1024;
    int dB1 = 16384 + 8192 + wid * 1024;

    // ---- ds_read bases (swizzle term (lr>>1)&3 is mi/ni-independent) ----
    int qs = (q ^ ((lr >> 1) & 3)) << 4;
    int A0 = (wr * 128 + lr) * 64 + qs;           // + mi*1024 imm
    int B0 = 16384 + (wc * 64 + lr) * 64 + qs;    // + ni*1024 imm

    f32x4 acc[8][4];
#pragma unroll
    for (int mi = 0; mi < 8; ++mi)
#pragma unroll
        for (int ni = 0; ni < 4; ++ni) acc[mi][ni] = (f32x4){0.f, 0.f, 0.f, 0.f};

    auto STAGE = [&](int ks, int bufi) {
        int kl = ks >> 4;
        int kh = (kl * 11) >> 5;     // kl/3 for kl in [0,9)
        int kw = kl - 3 * kh;
        int bko = (kh * 34 + kw) * 1024 + (ks & 15) * 64;
        int ao = ks * 64;
        char* L = lds + bufi * 32768;
        __builtin_amdgcn_global_load_lds(GPTR(GA + offA0 + ao), LPTR(L + dA0), 16, 0, 0);
        __builtin_amdgcn_global_load_lds(GPTR(GA + offA1 + ao), LPTR(L + dA1), 16, 0, 0);
        __builtin_amdgcn_global_load_lds(GPTR(GB + offB0 + bko), LPTR(L + dB0), 16, 0, 0);
        __builtin_amdgcn_global_load_lds(GPTR(GB + offB1 + bko), LPTR(L + dB1), 16, 0, 0);
    };

    short8 a0[8], b0[4], a1[8], b1[4];
    bool odd = (wid & 1);

#define READS(SETA, SETB, TT)                                                   \
    do {                                                                        \
        const char* L = lds + ((TT) & 3) * 32768;                               \
        _Pragma("unroll")                                                       \
        for (int mi = 0; mi < 8; ++mi) SETA[mi] = *(const short8*)(L + A0 + mi * 1024); \
        _Pragma("unroll")                                                       \
        for (int ni = 0; ni < 4; ++ni) SETB[ni] = *(const short8*)(L + B0 + ni * 1024); \
    } while (0)

#define MFMAS(SETA, SETB)                                                       \
    do {                                                                        \
        __builtin_amdgcn_s_setprio(1);                                          \
        _Pragma("unroll")                                                       \
        for (int mi = 0; mi < 8; ++mi)                                          \
            _Pragma("unroll")                                                   \
            for (int ni = 0; ni < 4; ++ni)                                      \
                acc[mi][ni] = __builtin_amdgcn_mfma_f32_16x16x32_bf16(          \
                    SETA[mi], SETB[ni], acc[mi][ni], 0, 0, 0);                  \
        __builtin_amdgcn_s_setprio(0);                                          \
    } while (0)

    // prologue: fill pipeline depth 2, load tile 0's fragments
    STAGE(0, 0);
    STAGE(1, 1);
    asm volatile("s_waitcnt vmcnt(4)" ::: "memory");   // tile 0 landed
    __builtin_amdgcn_s_barrier();
    __builtin_amdgcn_sched_barrier(0);
    READS(a0, b0, 0);

    for (int t = 0; t < NT; t += 2) {
        // ---- half 1: tile t (set0); prefetch reads t+1 -> set1 ----
        STAGE(t + 2 < NT ? t + 2 : NT - 1, (t + 2) & 3);
        asm volatile("s_waitcnt vmcnt(4)" ::: "memory");   // tile t+1 landed
        __builtin_amdgcn_s_barrier();
        __builtin_amdgcn_sched_barrier(0);
        if (odd) {
            READS(a1, b1, t + 1);
            __builtin_amdgcn_sched_barrier(0);
            MFMAS(a0, b0);
        } else {
            MFMAS(a0, b0);
            __builtin_amdgcn_sched_barrier(0);
            READS(a1, b1, t + 1);
        }

        // ---- half 2: tile t+1 (set1); prefetch reads t+2 -> set0 ----
        STAGE(t + 3 < NT ? t + 3 : NT - 1, (t + 3) & 3);
        asm volatile("s_waitcnt vmcnt(4)" ::: "memory");   // tile t+2 landed
        __builtin_amdgcn_s_barrier();
        __builtin_amdgcn_sched_barrier(0);
        if (odd) {
            READS(a0, b0, t + 2);
            __builtin_amdgcn_sched_barrier(0);
            MFMAS(a1, b1);
        } else {
            MFMAS(a1, b1);
            __builtin_amdgcn_sched_barrier(0);
            READS(a0, b0, t + 2);
        }
    }
    asm volatile("s_waitcnt vmcnt(0)" ::: "memory");   // drain clamped stages

    // ---- epilogue: 4 acc regs per frag = 4 parities of one oc -> 2x2 quad ----
    const float s2 = 1.41421356237309515f;
#pragma unroll
    for (int mi = 0; mi < 8; ++mi) {
        int oc = mt * 64 + wr * 32 + mi * 4 + q;
        float bv = bias[oc];
#pragma unroll
        for (int ni = 0; ni < 4; ++ni) {
            int n = nt * 256 + wc * 64 + ni * 16 + lr;
            int b = n >> 10, u = (n >> 5) & 31, v = n & 31;
            float y0 = acc[mi][ni][0] + bv;
            float y1 = acc[mi][ni][1] + bv;
            float y2 = acc[mi][ni][2] + bv;
            float y3 = acc[mi][ni][3] + bv;
            y0 = (y0 >= 0.f ? y0 : 0.2f * y0) * s2;
            y1 = (y1 >= 0.f ? y1 : 0.2f * y1) * s2;
            y2 = (y2 >= 0.f ? y2 : 0.2f * y2) * s2;
            y3 = (y3 >= 0.f ? y3 : 0.2f * y3) * s2;
            size_t base = (((size_t)b * OC + oc) * OHW + 2 * u) * OHW + 2 * v;
            *(f32x2*)(out + base)       = (f32x2){y0, y1};   // row 2u:   p=(0,0),(0,1)
            *(f32x2*)(out + base + OHW) = (f32x2){y2, y3};   // row 2u+1: p=(1,0),(1,1)
        }
    }
#undef READS
#undef MFMAS
}

// ---------------------------------------------------------------------------
extern "C" void kernel_launch(void* const* d_in, const int* in_sizes, int n_in,
                              void* d_out, int out_size, void* d_ws, size_t ws_size,
                              hipStream_t stream) {
    const float* x    = (const float*)d_in[0];
    const float* w    = (const float*)d_in[1];
    const float* bias = (const float*)d_in[2];
    float* out = (float*)d_out;

    __hip_bfloat16* xcl  = (__hip_bfloat16*)d_ws;
    __hip_bfloat16* Amat = (__hip_bfloat16*)((char*)d_ws + WS_AMAT_OFF);

    xprep<<<32 * 34, 256, 0, stream>>>(x, xcl);
    wtrans<<<(OC * IC) / 256, 256, 0, stream>>>(w, Amat);
    // grid: 4 M-tiles * 128 N-tiles = 512 blocks, 512 threads
    gemm_conv<<<512, 512, 0, stream>>>(Amat, xcl, bias, out);
}

// Round 11
// 285.004 us; speedup vs baseline: 11.7425x; 11.7425x over previous
//
#include <hip/hip_runtime.h>
#include <hip/hip_bf16.h>
#include <math.h>

// Problem constants
#define B_    32
#define IC    512
#define OC    256
#define HW    32
#define OHW   64

// ws layout:
//   xcl  at offset 0:          bf16 [32][34][34][512]  = 37,879,808 B (zero-padded channels-last)
//   Amat at offset 37,879,808: bf16 [1024][4608]       =  9,437,184 B
#define WS_AMAT_OFF 37879808ull

typedef __attribute__((ext_vector_type(8))) short short8;
typedef __attribute__((ext_vector_type(4))) float f32x4;
typedef __attribute__((ext_vector_type(2))) float f32x2;

#define GPTR(x) ((const __attribute__((address_space(1))) char*)(x))
#define LPTR(x) ((__attribute__((address_space(3))) char*)(x))

// ---------------------------------------------------------------------------
// Weight transform. M-row order (oc*4 + p): 4 consecutive C-rows per lane are
// the 4 parities of one oc -> coalesced 2x2 output quads in the epilogue.
__global__ __launch_bounds__(256) void wtrans(const float* __restrict__ w,
                                              __hip_bfloat16* __restrict__ Amat) {
    int t = blockIdx.x * blockDim.x + threadIdx.x;  // 131072 threads
    int ic = t & 511, oc = t >> 9;

    const float gain = 1.0f / sqrtf((float)(IC * 9));
    float wl[3][3];
    const float* wp = w + ((size_t)oc * IC + ic) * 9;
#pragma unroll
    for (int i = 0; i < 3; ++i)
#pragma unroll
        for (int j = 0; j < 3; ++j) wl[i][j] = wp[i * 3 + j] * gain;

    const float f1[4] = {1.f, 3.f, 3.f, 1.f};
    float g2[6][6];
#pragma unroll
    for (int s = 0; s < 6; ++s)
#pragma unroll
        for (int tt = 0; tt < 6; ++tt) {
            float acc = 0.f;
#pragma unroll
            for (int i = 0; i < 3; ++i)
#pragma unroll
                for (int j = 0; j < 3; ++j) {
                    int a = s - 2 + i, b = tt - 2 + j;
                    if (a >= 0 && a < 4 && b >= 0 && b < 4)
                        acc += wl[i][j] * f1[a] * f1[b] * 0.0625f;
                }
            g2[s][tt] = acc;
        }

#pragma unroll
    for (int pm = 0; pm < 2; ++pm)
#pragma unroll
        for (int pn = 0; pn < 2; ++pn)
#pragma unroll
            for (int k = 0; k < 3; ++k)
#pragma unroll
                for (int l = 0; l < 3; ++l) {
                    int p = pm * 2 + pn;
                    size_t idx = ((size_t)(oc * 4 + p) * 4608) + (k * 3 + l) * 512 + ic;
                    Amat[idx] = __float2bfloat16(g2[2 * k + 1 - pm][2 * l + 1 - pn]);
                }
}

// ---------------------------------------------------------------------------
// x (fp32 NCHW) -> xcl (bf16, [b][34][34][512], zero halo), via LDS transpose.
__global__ __launch_bounds__(256) void xprep(const float* __restrict__ x,
                                             __hip_bfloat16* __restrict__ xcl) {
    int blk = blockIdx.x;            // 32*34 blocks
    int b = blk / 34, h = blk % 34;
    __hip_bfloat16* orow = xcl + (size_t)(b * 34 + h) * 34 * 512;
    int t = threadIdx.x;
    bool hin = (h >= 1 && h <= 32);

    for (int i = t; i < 2 * 512; i += 256) {
        int wsel = i >> 9, ic = i & 511;
        orow[(size_t)(wsel * 33) * 512 + ic] = __float2bfloat16(0.f);
    }

    __shared__ float ls[16][33];
    int icl_r = t >> 5, wv_r = t & 31;
    int wv_w = t >> 3, icl_w = t & 7;

    for (int ic0 = 0; ic0 < 512; ic0 += 16) {
        __syncthreads();
#pragma unroll
        for (int pp = 0; pp < 2; ++pp) {
            int icll = icl_r + pp * 8;
            float v = 0.f;
            if (hin) v = x[(((size_t)b * IC + ic0 + icll) * HW + (h - 1)) * HW + wv_r];
            ls[icll][wv_r] = v;
        }
        __syncthreads();
#pragma unroll
        for (int pp = 0; pp < 2; ++pp) {
            int icll = icl_w + pp * 8;
            orow[(size_t)(wv_w + 1) * 512 + ic0 + icll] = __float2bfloat16(ls[icll][wv_w]);
        }
    }
}

// ---------------------------------------------------------------------------
// Implicit-GEMM, 256x256 tile, BK=64, 8 waves (2Mx4N), dbuf-2, 4 phases/tile
// (m201 template port), counted vmcnt(4) at ph1/ph3 ONLY (never 0 — fixes
// R6), k-half-plane LDS layout so each phase's staged plane is needed 3-4
// phases later, R4's verified zero-conflict swizzle (64-B rows), T5 setprio,
// XCD remap (R7-verified), coalesced quad epilogue.
//
// LDS buffer (64 KB): [A.kh0 16K | A.kh1 16K | B.kh0 16K | B.kh1 16K],
// 2 buffers = 128 KB. Plane row = 64 B = 4 granules; granule g of row r
// stored at slot g ^ ((r>>1)&3) (both-sides swizzle, zero-conflict per R4).
//
// Per tile T (read buf T&1, stage T+1 into buf^1):
//  ph0: read B.kh0(4) + A.mh0.kh0(4); stage A.kh0(T+1);            bar;lgkm;16 MFMA;bar
//  ph1: read A.mh1.kh0(4);            stage B.kh0(T+1); vmcnt(4);  bar;lgkm;16 MFMA;bar
//  ph2: read B.kh1(4) + A.mh0.kh1(4); stage A.kh1(T+1);            bar;lgkm;16 MFMA;bar
//  ph3: read A.mh1.kh1(4);            stage B.kh1(T+1); vmcnt(4);  bar;lgkm;16 MFMA;bar
// vmcnt(4)+barrier is a collective guarantee: every wave's oldest 4 loads
// (the planes needed by the NEXT two phases) have landed.
__global__ __launch_bounds__(512, 2) void gemm_conv(const __hip_bfloat16* __restrict__ Amat,
                                                    const __hip_bfloat16* __restrict__ xcl,
                                                    const float* __restrict__ bias,
                                                    float* __restrict__ out) {
    __shared__ __align__(1024) char lds[2 * 65536];

    const int NT = 72;               // K-tiles of 64 (K = 4608)
    int bid = blockIdx.x;
    // XCD remap (verified R7: FETCH 610->281 MB)
    int mt = bid >> 7;               // 0..3
    int nt = (bid & 7) * 16 + ((bid >> 3) & 15);  // 0..127
    int tid = threadIdx.x;
    int wid = tid >> 6;
    int lane = tid & 63;
    int wr = wid >> 2;               // 0..1  (M half)
    int wc = wid & 3;                // 0..3  (N quarter)
    int q = lane >> 4;               // k-granule within a 64-B k-half
    int lr = lane & 15;

    // ---- staging constants (swizzle folded into global source) ----
    int rr0 = tid >> 2;              // 0..127 (chunk i adds 128)
    int slt = tid & 3;               // LDS slot within 64-B row
    int g_ = slt ^ ((rr0 >> 1) & 3); // source granule ((rr0+128)>>1 has same &3)

    const char* GA = (const char*)Amat;
    const char* GB = (const char*)xcl;

    size_t asrc[2];
    int bsrc[2];
#pragma unroll
    for (int i = 0; i < 2; ++i) {
        int rr = i * 128 + rr0;
        asrc[i] = (size_t)(mt * 256 + rr) * 9216 + g_ * 16;
        int n = nt * 256 + rr;
        int bb = n >> 10, uu = (n >> 5) & 31, vv = n & 31;
        bsrc[i] = ((bb * 34 + uu) * 34 + vv) * 1024 + g_ * 16;
    }
    int d0 = rr0 * 64 + slt * 16;    // dest within plane; chunk i adds 8192

    // ---- ds_read bases within a plane (R4 zero-conflict swizzle) ----
    int swz = (q ^ ((lr >> 1) & 3)) << 4;
    int ArdRow = (wr * 128 + lr) * 64 + swz;   // + mi*1024 (+4096 for mh1)
    int BrdRow = (wc * 64 + lr) * 64 + swz;    // + ni*1024

    f32x4 acc[8][4];
#pragma unroll
    for (int mi = 0; mi < 8; ++mi)
#pragma unroll
        for (int ni = 0; ni < 4; ++ni) acc[mi][ni] = (f32x4){0.f, 0.f, 0.f, 0.f};

    auto STAGE_A = [&](int T1, int ks) {     // one A plane = 2 loads/thread
        size_t ao = (size_t)T1 * 128 + ks * 64;
        char* dst = lds + ((T1 & 1) << 16) + ks * 16384 + d0;
        __builtin_amdgcn_global_load_lds(GPTR(GA + asrc[0] + ao), LPTR(dst), 16, 0, 0);
        __builtin_amdgcn_global_load_lds(GPTR(GA + asrc[1] + ao), LPTR(dst + 8192), 16, 0, 0);
    };
    auto STAGE_B = [&](int T1, int ks) {     // one B plane = 2 loads/thread
        int kl = T1 >> 3;
        int kh = (kl * 11) >> 5;             // kl/3 for kl in [0,9)
        int kw = kl - 3 * kh;
        int bo = (kh * 34 + kw) * 1024 + (T1 & 7) * 128 + ks * 64;
        char* dst = lds + ((T1 & 1) << 16) + 32768 + ks * 16384 + d0;
        __builtin_amdgcn_global_load_lds(GPTR(GB + bsrc[0] + bo), LPTR(dst), 16, 0, 0);
        __builtin_amdgcn_global_load_lds(GPTR(GB + bsrc[1] + bo), LPTR(dst + 8192), 16, 0, 0);
    };

#define LGKM0() do { asm volatile("s_waitcnt lgkmcnt(0)" ::: "memory"); \
                     __builtin_amdgcn_sched_barrier(0); } while (0)
#define MFMA16(MOFF, AARR, BARR)                                               \
    do {                                                                       \
        __builtin_amdgcn_s_setprio(1);                                         \
        _Pragma("unroll")                                                      \
        for (int mi = 0; mi < 4; ++mi)                                         \
            _Pragma("unroll")                                                  \
            for (int ni = 0; ni < 4; ++ni)                                     \
                acc[(MOFF) + mi][ni] = __builtin_amdgcn_mfma_f32_16x16x32_bf16(\
                    AARR[mi], BARR[ni], acc[(MOFF) + mi][ni], 0, 0, 0);        \
        __builtin_amdgcn_s_setprio(0);                                         \
    } while (0)

    // prologue: stage tile 0 fully; wait for its kh0 planes; barrier
    STAGE_A(0, 0);
    STAGE_B(0, 0);
    STAGE_A(0, 1);
    STAGE_B(0, 1);
    asm volatile("s_waitcnt vmcnt(4)" ::: "memory");
    __builtin_amdgcn_s_barrier();

    for (int T = 0; T < NT; ++T) {
        int bb = (T & 1) << 16;
        const char* Akh0 = lds + bb;
        const char* Akh1 = lds + bb + 16384;
        const char* Bkh0 = lds + bb + 32768;
        const char* Bkh1 = lds + bb + 49152;
        short8 aF[4], bF[4];

        // ---- ph0: B.kh0 + A.mh0.kh0 ----
#pragma unroll
        for (int ni = 0; ni < 4; ++ni) bF[ni] = *(const short8*)(Bkh0 + BrdRow + ni * 1024);
#pragma unroll
        for (int mi = 0; mi < 4; ++mi) aF[mi] = *(const short8*)(Akh0 + ArdRow + mi * 1024);
        if (T + 1 < NT) STAGE_A(T + 1, 0);
        __builtin_amdgcn_s_barrier();
        LGKM0();
        MFMA16(0, aF, bF);
        __builtin_amdgcn_s_barrier();

        // ---- ph1: A.mh1.kh0 ----
#pragma unroll
        for (int mi = 0; mi < 4; ++mi)
            aF[mi] = *(const short8*)(Akh0 + ArdRow + 4096 + mi * 1024);
        if (T + 1 < NT) STAGE_B(T + 1, 0);
        asm volatile("s_waitcnt vmcnt(4)" ::: "memory");  // kh1 planes of T landed
        __builtin_amdgcn_s_barrier();
        LGKM0();
        MFMA16(4, aF, bF);
        __builtin_amdgcn_s_barrier();

        // ---- ph2: B.kh1 + A.mh0.kh1 ----
#pragma unroll
        for (int ni = 0; ni < 4; ++ni) bF[ni] = *(const short8*)(Bkh1 + BrdRow + ni * 1024);
#pragma unroll
        for (int mi = 0; mi < 4; ++mi) aF[mi] = *(const short8*)(Akh1 + ArdRow + mi * 1024);
        if (T + 1 < NT) STAGE_A(T + 1, 1);
        __builtin_amdgcn_s_barrier();
        LGKM0();
        MFMA16(0, aF, bF);
        __builtin_amdgcn_s_barrier();

        // ---- ph3: A.mh1.kh1 ----
#pragma unroll
        for (int mi = 0; mi < 4; ++mi)
            aF[mi] = *(const short8*)(Akh1 + ArdRow + 4096 + mi * 1024);
        if (T + 1 < NT) STAGE_B(T + 1, 1);
        asm volatile("s_waitcnt vmcnt(4)" ::: "memory");  // kh0 planes of T+1 landed
        __builtin_amdgcn_s_barrier();
        LGKM0();
        MFMA16(4, aF, bF);
        __builtin_amdgcn_s_barrier();
    }
    asm volatile("s_waitcnt vmcnt(0)" ::: "memory");

    // ---- epilogue: 4 acc regs per frag = 4 parities of one oc -> 2x2 quad ----
    const float s2 = 1.41421356237309515f;
#pragma unroll
    for (int mi = 0; mi < 8; ++mi) {
        int oc = mt * 64 + wr * 32 + mi * 4 + q;
        float bv = bias[oc];
#pragma unroll
        for (int ni = 0; ni < 4; ++ni) {
            int n = nt * 256 + wc * 64 + ni * 16 + lr;
            int b = n >> 10, u = (n >> 5) & 31, v = n & 31;
            float y0 = acc[mi][ni][0] + bv;
            float y1 = acc[mi][ni][1] + bv;
            float y2 = acc[mi][ni][2] + bv;
            float y3 = acc[mi][ni][3] + bv;
            y0 = (y0 >= 0.f ? y0 : 0.2f * y0) * s2;
            y1 = (y1 >= 0.f ? y1 : 0.2f * y1) * s2;
            y2 = (y2 >= 0.f ? y2 : 0.2f * y2) * s2;
            y3 = (y3 >= 0.f ? y3 : 0.2f * y3) * s2;
            size_t base = (((size_t)b * OC + oc) * OHW + 2 * u) * OHW + 2 * v;
            *(f32x2*)(out + base)       = (f32x2){y0, y1};   // row 2u:   p=(0,0),(0,1)
            *(f32x2*)(out + base + OHW) = (f32x2){y2, y3};   // row 2u+1: p=(1,0),(1,1)
        }
    }
#undef LGKM0
#undef MFMA16
}

// ---------------------------------------------------------------------------
extern "C" void kernel_launch(void* const* d_in, const int* in_sizes, int n_in,
                              void* d_out, int out_size, void* d_ws, size_t ws_size,
                              hipStream_t stream) {
    const float* x    = (const float*)d_in[0];
    const float* w    = (const float*)d_in[1];
    const float* bias = (const float*)d_in[2];
    float* out = (float*)d_out;

    __hip_bfloat16* xcl  = (__hip_bfloat16*)d_ws;
    __hip_bfloat16* Amat = (__hip_bfloat16*)((char*)d_ws + WS_AMAT_OFF);

    xprep<<<32 * 34, 256, 0, stream>>>(x, xcl);
    wtrans<<<(OC * IC) / 256, 256, 0, stream>>>(w, Amat);
    // grid: 4 M-tiles * 128 N-tiles = 512 blocks, 512 threads
    gemm_conv<<<512, 512, 0, stream>>>(Amat, xcl, bias, out);
}